// Round 1
// baseline (963.566 us; speedup 1.0000x reference)
//
#include <hip/hip_runtime.h>

// DecoderLSTM: 30-step LSTM decoder, 8192 independent pedestrians, H=256, E=64.
// Persistent kernel: 256 blocks x 512 threads (8 waves), 32 peds/block.
// Wave w owns unit-columns [w*32, w*32+32) of ALL FOUR gates -> i,f,g,o for a
// given (ped,unit) live in the same lane/register. c stays in fp32 registers.
// Weights pre-shuffled to bf16 MFMA-B-fragment-linear layout in d_ws.

typedef float  f32x4  __attribute__((ext_vector_type(4)));
typedef short  short8 __attribute__((ext_vector_type(8)));
typedef __bf16 bf16x8 __attribute__((ext_vector_type(8)));

#define WS_WHH_OFF 0
#define WS_WIH_OFF (512 * 1024)
#define WS_BIAS_OFF (640 * 1024)
#define WS_SCAL_OFF (640 * 1024 + 4096)

__device__ __forceinline__ unsigned short f2bf(float f) {
  unsigned int u = __float_as_uint(f);
  u += 0x7FFFu + ((u >> 16) & 1u);   // round-to-nearest-even
  return (unsigned short)(u >> 16);
}

__device__ __forceinline__ float sigm(float x) {
  return __builtin_amdgcn_rcpf(1.0f + __expf(-x));
}

__device__ __forceinline__ float tanh_(float x) {
  float ax = fabsf(x);
  float t = __expf(-2.0f * ax);
  float r = (1.0f - t) * __builtin_amdgcn_rcpf(1.0f + t);
  return x >= 0.0f ? r : -r;
}

__device__ __forceinline__ f32x4 mfma16(short8 a, short8 b, f32x4 c) {
  return __builtin_amdgcn_mfma_f32_16x16x32_bf16(
      __builtin_bit_cast(bf16x8, a), __builtin_bit_cast(bf16x8, b), c, 0, 0, 0);
}

// ---------------- Prologue 1: shuffle weights into B-frag-linear bf16 -------
// whh_s linear idx: (((w*8 + kc)*4 + g)*2 + nt2)*512 + l*8 + j
//   row = g*256 + w*32 + nt2*16 + (l&15), col = kc*32 + (l>>4)*8 + j
// wih_s linear idx: (((w*2 + kc2)*4 + g)*2 + nt2)*512 + l*8 + j (col in [0,64))
extern "C" __global__ void shuffle_weights(const float* __restrict__ Wih,
                                           const float* __restrict__ Whh,
                                           unsigned short* __restrict__ whh_s,
                                           unsigned short* __restrict__ wih_s) {
  int t = blockIdx.x * 256 + threadIdx.x;
  if (t < 32768) {
    int l = t & 63; int x = t >> 6;
    int nt2 = x & 1; x >>= 1;
    int g = x & 3;  x >>= 2;
    int kc = x & 7; x >>= 3;
    int w = x;  // 0..7
    int row = g * 256 + w * 32 + nt2 * 16 + (l & 15);
    int col0 = kc * 32 + (l >> 4) * 8;
    const float* src = Whh + row * 256 + col0;
    unsigned short* dst = whh_s + t * 8;
#pragma unroll
    for (int j = 0; j < 8; j++) dst[j] = f2bf(src[j]);
  } else if (t < 40960) {
    int t2 = t - 32768;
    int l = t2 & 63; int x = t2 >> 6;
    int nt2 = x & 1; x >>= 1;
    int g = x & 3;   x >>= 2;
    int kc2 = x & 1; x >>= 1;
    int w = x;  // 0..7
    int row = g * 256 + w * 32 + nt2 * 16 + (l & 15);
    int col0 = kc2 * 32 + (l >> 4) * 8;
    const float* src = Wih + row * 64 + col0;
    unsigned short* dst = wih_s + t2 * 8;
#pragma unroll
    for (int j = 0; j < 8; j++) dst[j] = f2bf(src[j]);
  }
}

// ---------------- Prologue 2: bias = b_ih+b_hh; K/SP reductions -------------
// scal = {K0, K1, SP0, SP1}; K_r = sum_u ln2_b[u]*posW[r][u],
// SP_r = sum_u ln2_g[u]*posW[r][u]
extern "C" __global__ void prologue2(const float* __restrict__ b_ih,
                                     const float* __restrict__ b_hh,
                                     const float* __restrict__ ln2g,
                                     const float* __restrict__ ln2b,
                                     const float* __restrict__ posW,
                                     float* __restrict__ biasv,
                                     float* __restrict__ scal) {
  int t = threadIdx.x;  // 256 threads
#pragma unroll
  for (int k2 = 0; k2 < 4; k2++) {
    int n = t * 4 + k2;
    biasv[n] = b_ih[n] + b_hh[n];
  }
  __shared__ float red[256][4];
  float g = ln2g[t], b = ln2b[t], p0 = posW[t], p1 = posW[256 + t];
  red[t][0] = b * p0;
  red[t][1] = b * p1;
  red[t][2] = g * p0;
  red[t][3] = g * p1;
  __syncthreads();
  for (int s = 128; s > 0; s >>= 1) {
    if (t < s) {
#pragma unroll
      for (int v = 0; v < 4; v++) red[t][v] += red[t + s][v];
    }
    __syncthreads();
  }
  if (t == 0) {
#pragma unroll
    for (int v = 0; v < 4; v++) scal[v] = red[0][v];
  }
}

// ---------------- Main persistent decoder kernel ----------------------------
extern "C" __global__ __launch_bounds__(512, 2) void decoder_main(
    const float* __restrict__ lpr,   // last_pos_rel [8192][2]
    const float* __restrict__ h0,    // [8192][256]
    const float* __restrict__ c0,    // [8192][256]
    const float* __restrict__ embW,  // [64][2]
    const float* __restrict__ embB,  // [64]
    const float* __restrict__ ln1g, const float* __restrict__ ln1b,  // [2]
    const float* __restrict__ posW,  // [2][256]
    const float* __restrict__ posB,  // [2]
    const float* __restrict__ ln2g,  // [256]
    const unsigned short* __restrict__ whh_s,
    const unsigned short* __restrict__ wih_s,
    const float* __restrict__ biasv,  // [1024]
    const float* __restrict__ scal,   // [4] {K0,K1,SP0,SP1}
    float* __restrict__ out)          // [30][8192][2]
{
  // LDS
  __shared__ unsigned short h_stage[16 * 512];  // (mtA*8+kc) chunks, A-frag linear, bf16
  __shared__ unsigned short x_stage[4 * 512];   // (mtA*2+kc2) chunks
  __shared__ float h_lds[32 * 260];             // fp32 h, padded stride 260
  __shared__ float partials[32 * 33];           // [ped][w*4+v], padded stride 33
  __shared__ float n01[32][2];                  // LN1'd rel per ped

  const int tid = threadIdx.x;
  const int w = tid >> 6;      // wave 0..7
  const int l = tid & 63;      // lane
  const int q = l >> 4;        // quad
  const int i = l & 15;
  const int P0 = blockIdx.x * 32;

  // phase-C mapping: 16 threads per ped
  const int pc = tid >> 4;     // ped 0..31
  const int s2 = tid & 15;

  // ---- constants into registers ----
  const float K0 = scal[0], K1 = scal[1], SP0 = scal[2], SP1 = scal[3];
  const float pb0 = posB[0], pb1 = posB[1];
  const float g10 = ln1g[0], g11 = ln1g[1], b10 = ln1b[0], b11 = ln1b[1];

  float bias_r[4][2];
#pragma unroll
  for (int g = 0; g < 4; g++)
#pragma unroll
    for (int nt2 = 0; nt2 < 2; nt2++)
      bias_r[g][nt2] = biasv[g * 256 + w * 32 + nt2 * 16 + i];

  float Pp[2][2];  // [nt2][r]: ln2_g[u]*posW[r][u] at u = w*32+nt2*16+i
#pragma unroll
  for (int nt2 = 0; nt2 < 2; nt2++) {
    int u = w * 32 + nt2 * 16 + i;
    float gg = ln2g[u];
    Pp[nt2][0] = gg * posW[u];
    Pp[nt2][1] = gg * posW[256 + u];
  }

  // embed constants for phase C (k = s2*4 + jj)
  float ew0[4], ew1[4], eb[4];
#pragma unroll
  for (int jj = 0; jj < 4; jj++) {
    int k = s2 * 4 + jj;
    ew0[jj] = embW[k * 2];
    ew1[jj] = embW[k * 2 + 1];
    eb[jj] = embB[k];
  }

  // ---- c0 into C-layout registers ----
  f32x4 c_r[2][2];  // [mt][nt2], components = r
#pragma unroll
  for (int mt = 0; mt < 2; mt++)
#pragma unroll
    for (int nt2 = 0; nt2 < 2; nt2++)
#pragma unroll
      for (int r = 0; r < 4; r++)
        c_r[mt][nt2][r] =
            c0[(P0 + mt * 16 + q * 4 + r) * 256 + w * 32 + nt2 * 16 + i];

  // ---- stage h0 (bf16 A-frag layout) ----
#pragma unroll
  for (int hh = 0; hh < 2; hh++) {
    float tf[8];
    const float* src = h0 + (size_t)(P0 + pc) * 256 + s2 * 16 + hh * 8;
    *(float4*)&tf[0] = *(const float4*)(src);
    *(float4*)&tf[4] = *(const float4*)(src + 4);
    short8 sv;
#pragma unroll
    for (int j = 0; j < 8; j++) sv[j] = (short)f2bf(tf[j]);
    int chunk = (pc >> 4) * 8 + (s2 >> 1);
    int slot = (pc & 15) + 16 * ((s2 & 1) * 2 + hh);
    *(short8*)(h_stage + chunk * 512 + slot * 8) = sv;
  }

  // ---- stage x0 = embed(LN1(last_pos_rel)) ----
  {
    float r0 = lpr[(P0 + pc) * 2], r1 = lpr[(P0 + pc) * 2 + 1];
    float d = 0.5f * (r0 - r1);
    float rs = rsqrtf(d * d + 1e-5f);
    float n0 = d * rs * g10 + b10;
    float n1 = -d * rs * g11 + b11;
    ushort4 xt;
    float e0 = n0 * ew0[0] + n1 * ew1[0] + eb[0]; e0 = e0 > 0.f ? e0 : 0.01f * e0;
    float e1 = n0 * ew0[1] + n1 * ew1[1] + eb[1]; e1 = e1 > 0.f ? e1 : 0.01f * e1;
    float e2 = n0 * ew0[2] + n1 * ew1[2] + eb[2]; e2 = e2 > 0.f ? e2 : 0.01f * e2;
    float e3 = n0 * ew0[3] + n1 * ew1[3] + eb[3]; e3 = e3 > 0.f ? e3 : 0.01f * e3;
    xt.x = f2bf(e0); xt.y = f2bf(e1); xt.z = f2bf(e2); xt.w = f2bf(e3);
    int chunk = (pc >> 4) * 2 + (s2 >> 3);
    int slot = (pc & 15) + 16 * ((s2 & 7) >> 1);
    int j0 = (s2 & 1) * 4;
    *(ushort4*)(x_stage + chunk * 512 + slot * 8 + j0) = xt;
  }

  const unsigned short* wihW = wih_s + w * (2 * 4 * 2 * 512);
  const unsigned short* whhW = whh_s + w * (8 * 4 * 2 * 512);
  const int loff = l * 8;
  const int u2base = w * 32 + i;

  __syncthreads();

  for (int st = 0; st < 30; st++) {
    // ---- acc init with bias ----
    f32x4 acc[4][2][2];
#pragma unroll
    for (int g = 0; g < 4; g++)
#pragma unroll
      for (int mt = 0; mt < 2; mt++)
#pragma unroll
        for (int nt2 = 0; nt2 < 2; nt2++) {
          float bv = bias_r[g][nt2];
          acc[g][mt][nt2] = (f32x4){bv, bv, bv, bv};
        }

    // ---- X @ W_ih^T ----
#pragma unroll
    for (int kc2 = 0; kc2 < 2; kc2++) {
      short8 a0 = *(const short8*)(x_stage + (0 * 2 + kc2) * 512 + loff);
      short8 a1 = *(const short8*)(x_stage + (1 * 2 + kc2) * 512 + loff);
#pragma unroll
      for (int g = 0; g < 4; g++)
#pragma unroll
        for (int nt2 = 0; nt2 < 2; nt2++) {
          short8 b = *(const short8*)(wihW + (kc2 * 8 + g * 2 + nt2) * 512 + loff);
          acc[g][0][nt2] = mfma16(a0, b, acc[g][0][nt2]);
          acc[g][1][nt2] = mfma16(a1, b, acc[g][1][nt2]);
        }
    }
    // ---- H @ W_hh^T ----
#pragma unroll
    for (int kc = 0; kc < 8; kc++) {
      short8 a0 = *(const short8*)(h_stage + (0 * 8 + kc) * 512 + loff);
      short8 a1 = *(const short8*)(h_stage + (1 * 8 + kc) * 512 + loff);
#pragma unroll
      for (int g = 0; g < 4; g++)
#pragma unroll
        for (int nt2 = 0; nt2 < 2; nt2++) {
          short8 b = *(const short8*)(whhW + (kc * 8 + g * 2 + nt2) * 512 + loff);
          acc[g][0][nt2] = mfma16(a0, b, acc[g][0][nt2]);
          acc[g][1][nt2] = mfma16(a1, b, acc[g][1][nt2]);
        }
    }

    // ---- Phase A: LSTM cell update (in C-layout registers) ----
    float sh[2][4], sh2[2][4], sA[2][4], sB[2][4];
#pragma unroll
    for (int mt = 0; mt < 2; mt++)
#pragma unroll
      for (int r = 0; r < 4; r++) {
        sh[mt][r] = 0.f; sh2[mt][r] = 0.f; sA[mt][r] = 0.f; sB[mt][r] = 0.f;
      }

#pragma unroll
    for (int mt = 0; mt < 2; mt++)
#pragma unroll
      for (int nt2 = 0; nt2 < 2; nt2++)
#pragma unroll
        for (int r = 0; r < 4; r++) {
          float iv = sigm(acc[0][mt][nt2][r]);
          float fv = sigm(acc[1][mt][nt2][r]);
          float gv = tanh_(acc[2][mt][nt2][r]);
          float ov = sigm(acc[3][mt][nt2][r]);
          float cc = fv * c_r[mt][nt2][r] + iv * gv;
          c_r[mt][nt2][r] = cc;
          float hv = ov * tanh_(cc);
          h_lds[(mt * 16 + q * 4 + r) * 260 + u2base + nt2 * 16] = hv;
          sh[mt][r] += hv;
          sh2[mt][r] += hv * hv;
          sA[mt][r] += hv * Pp[nt2][0];
          sB[mt][r] += hv * Pp[nt2][1];
        }

    // in-wave reduce across the 16 lanes of each quad-row (i dimension)
#pragma unroll
    for (int mask = 1; mask <= 8; mask <<= 1) {
#pragma unroll
      for (int mt = 0; mt < 2; mt++)
#pragma unroll
        for (int r = 0; r < 4; r++) {
          sh[mt][r] += __shfl_xor(sh[mt][r], mask, 64);
          sh2[mt][r] += __shfl_xor(sh2[mt][r], mask, 64);
          sA[mt][r] += __shfl_xor(sA[mt][r], mask, 64);
          sB[mt][r] += __shfl_xor(sB[mt][r], mask, 64);
        }
    }
    if (i == 0) {
#pragma unroll
      for (int mt = 0; mt < 2; mt++)
#pragma unroll
        for (int r = 0; r < 4; r++) {
          int pp = mt * 16 + q * 4 + r;
          partials[pp * 33 + w * 4 + 0] = sh[mt][r];
          partials[pp * 33 + w * 4 + 1] = sh2[mt][r];
          partials[pp * 33 + w * 4 + 2] = sA[mt][r];
          partials[pp * 33 + w * 4 + 3] = sB[mt][r];
        }
    }
    __syncthreads();

    // ---- Phase B: LN2 + pos head + output + LN1 (32 threads) ----
    if (tid < 32) {
      int p = tid;
      float S = 0.f, S2 = 0.f, D0 = 0.f, D1 = 0.f;
#pragma unroll
      for (int ww = 0; ww < 8; ww++) {
        S += partials[p * 33 + ww * 4 + 0];
        S2 += partials[p * 33 + ww * 4 + 1];
        D0 += partials[p * 33 + ww * 4 + 2];
        D1 += partials[p * 33 + ww * 4 + 3];
      }
      float mu = S * (1.0f / 256.0f);
      float var = S2 * (1.0f / 256.0f) - mu * mu;
      float rsig = rsqrtf(var + 1e-5f);
      float dot0 = rsig * (D0 - mu * SP0) + K0;
      float dot1 = rsig * (D1 - mu * SP1) + K1;
      float rel0 = sigm(dot0 + pb0);
      float rel1 = sigm(dot1 + pb1);
      *(float2*)(out + (size_t)st * 16384 + (P0 + p) * 2) =
          make_float2(rel0, rel1);
      // LN1 of [rel0, rel1]
      float d = 0.5f * (rel0 - rel1);
      float rs = rsqrtf(d * d + 1e-5f);
      n01[p][0] = d * rs * g10 + b10;
      n01[p][1] = -d * rs * g11 + b11;
    }
    __syncthreads();

    // ---- Phase C: restage h (bf16 A-frags) + next x = embed(n01) ----
    {
#pragma unroll
      for (int hh = 0; hh < 2; hh++) {
        const float* src = &h_lds[pc * 260 + s2 * 16 + hh * 8];
        short8 sv;
#pragma unroll
        for (int j = 0; j < 8; j++) sv[j] = (short)f2bf(src[j]);
        int chunk = (pc >> 4) * 8 + (s2 >> 1);
        int slot = (pc & 15) + 16 * ((s2 & 1) * 2 + hh);
        *(short8*)(h_stage + chunk * 512 + slot * 8) = sv;
      }
      float n0 = n01[pc][0], n1 = n01[pc][1];
      ushort4 xt;
      float e0 = n0 * ew0[0] + n1 * ew1[0] + eb[0]; e0 = e0 > 0.f ? e0 : 0.01f * e0;
      float e1 = n0 * ew0[1] + n1 * ew1[1] + eb[1]; e1 = e1 > 0.f ? e1 : 0.01f * e1;
      float e2 = n0 * ew0[2] + n1 * ew1[2] + eb[2]; e2 = e2 > 0.f ? e2 : 0.01f * e2;
      float e3 = n0 * ew0[3] + n1 * ew1[3] + eb[3]; e3 = e3 > 0.f ? e3 : 0.01f * e3;
      xt.x = f2bf(e0); xt.y = f2bf(e1); xt.z = f2bf(e2); xt.w = f2bf(e3);
      int chunk = (pc >> 4) * 2 + (s2 >> 3);
      int slot = (pc & 15) + 16 * ((s2 & 7) >> 1);
      int j0 = (s2 & 1) * 4;
      *(ushort4*)(x_stage + chunk * 512 + slot * 8 + j0) = xt;
    }
    __syncthreads();
  }
}

extern "C" void kernel_launch(void* const* d_in, const int* in_sizes, int n_in,
                              void* d_out, int out_size, void* d_ws,
                              size_t ws_size, hipStream_t stream) {
  (void)in_sizes; (void)n_in; (void)out_size; (void)ws_size;
  const float* lpr  = (const float*)d_in[1];
  const float* h0   = (const float*)d_in[2];
  const float* c0   = (const float*)d_in[3];
  const float* Wih  = (const float*)d_in[4];
  const float* Whh  = (const float*)d_in[5];
  const float* b_ih = (const float*)d_in[6];
  const float* b_hh = (const float*)d_in[7];
  const float* embW = (const float*)d_in[8];
  const float* embB = (const float*)d_in[9];
  const float* ln1g = (const float*)d_in[10];
  const float* ln1b = (const float*)d_in[11];
  const float* posW = (const float*)d_in[12];
  const float* posB = (const float*)d_in[13];
  const float* ln2g = (const float*)d_in[14];
  const float* ln2b = (const float*)d_in[15];

  char* ws = (char*)d_ws;
  unsigned short* whh_s = (unsigned short*)(ws + WS_WHH_OFF);
  unsigned short* wih_s = (unsigned short*)(ws + WS_WIH_OFF);
  float* biasv = (float*)(ws + WS_BIAS_OFF);
  float* scal  = (float*)(ws + WS_SCAL_OFF);

  shuffle_weights<<<dim3(160), dim3(256), 0, stream>>>(Wih, Whh, whh_s, wih_s);
  prologue2<<<dim3(1), dim3(256), 0, stream>>>(b_ih, b_hh, ln2g, ln2b, posW,
                                               biasv, scal);
  decoder_main<<<dim3(256), dim3(512), 0, stream>>>(
      lpr, h0, c0, embW, embB, ln1g, ln1b, posW, posB, ln2g, whh_s, wih_s,
      biasv, scal, (float*)d_out);
}